// Round 1
// baseline (1027.901 us; speedup 1.0000x reference)
//
#include <hip/hip_runtime.h>

#define N_NODES 3072
#define N_EDGES 3072
#define N_LG    6144
#define F       64
#define H       4

// workspace layout (float offsets)
#define OFF_PQ   0                                  // 2 kinds * H*N*F = 1572864
#define OFF_PV   (OFF_PQ + 2*H*N_NODES*F)           // 1572864
#define OFF_PK   (OFF_PV + 2*H*N_NODES*F)           // 2 kinds * H*N = 24576
#define OFF_SRK  (OFF_PK + 2*H*N_NODES)             // 2*H*F = 512
#define OFF_ATT  (OFF_SRK + 2*H*F)                  // 2 kinds * H*N = 24576
#define OFF_WING (OFF_ATT + 2*H*N_NODES)            // N_EDGES ints
#define OFF_WINLG (OFF_WING + N_EDGES)              // N_LG ints

__global__ void zero_kernel(float4* __restrict__ out) {
    out[blockIdx.x * 256 + threadIdx.x] = make_float4(0.f, 0.f, 0.f, 0.f);
}

// grid (3072, 2); block 576. t<256: q col, t<512: v col, t<516: k col.
__global__ __launch_bounds__(576) void proj_kernel(
    const float* __restrict__ node_in, const float* __restrict__ edge_in,
    const float* __restrict__ nqW, const float* __restrict__ nqb,
    const float* __restrict__ nkW, const float* __restrict__ nkb,
    const float* __restrict__ nvW, const float* __restrict__ nvb,
    const float* __restrict__ eqW, const float* __restrict__ eqb,
    const float* __restrict__ ekW, const float* __restrict__ ekb,
    const float* __restrict__ evW, const float* __restrict__ evb,
    float* __restrict__ ws)
{
    const int row = blockIdx.x;
    const int kind = blockIdx.y;
    const int tid = threadIdx.x;
    __shared__ float r[F];
    const float* in = kind ? edge_in : node_in;
    if (tid < F) r[tid] = in[row * F + tid];
    __syncthreads();
    const float* W; const float* b; float* out; int ncols, col;
    if (tid < 256) {
        W = kind ? eqW : nqW; b = kind ? eqb : nqb;
        out = ws + OFF_PQ + (size_t)kind * H * N_NODES * F; ncols = 256; col = tid;
    } else if (tid < 512) {
        W = kind ? evW : nvW; b = kind ? evb : nvb;
        out = ws + OFF_PV + (size_t)kind * H * N_NODES * F; ncols = 256; col = tid - 256;
    } else if (tid < 516) {
        W = kind ? ekW : nkW; b = kind ? ekb : nkb;
        out = ws + OFF_PK + (size_t)kind * H * N_NODES; ncols = 4; col = tid - 512;
    } else return;
    float acc = b[col];
    #pragma unroll
    for (int k = 0; k < F; ++k) acc += r[k] * W[k * ncols + col];
    out[row * ncols + col] = acc;
}

// srk[h,f] = sum_m SR[m,f] * K[h*M+m].  grid (H, 2); block 256 (f = t&63, chunk = t>>6)
__global__ __launch_bounds__(256) void srk_kernel(
    const float* __restrict__ node_in, const float* __restrict__ edge_in,
    float* __restrict__ ws)
{
    const int h = blockIdx.x, kind = blockIdx.y, tid = threadIdx.x;
    const int f = tid & 63, c = tid >> 6;
    const float* SR = kind ? edge_in : node_in;
    const float* K = ws + OFF_PK + kind * H * N_NODES + h * N_NODES;
    float acc = 0.f;
    const int m0 = c * (N_NODES / 4);
    for (int m = m0; m < m0 + N_NODES / 4; ++m)
        acc += SR[m * F + f] * K[m];
    __shared__ float red[256];
    red[tid] = acc;
    __syncthreads();
    if (c == 0)
        ws[OFF_SRK + (kind * H + h) * F + f] = red[f] + red[64 + f] + red[128 + f] + red[192 + f];
}

// x[m] = dot(Q[h,m,:], srk)/8; softmax over m=3072.  grid (H,2); block 1024, 3 m/thread
__global__ __launch_bounds__(1024) void att_kernel(float* __restrict__ ws)
{
    const int h = blockIdx.x, kind = blockIdx.y, tid = threadIdx.x;
    const float* Q = ws + OFF_PQ + (size_t)kind * H * N_NODES * F + (size_t)h * N_NODES * F;
    float* att = ws + OFF_ATT + kind * H * N_NODES + h * N_NODES;
    __shared__ float s_srk[F];
    __shared__ float sred[16];
    if (tid < F) s_srk[tid] = ws[OFF_SRK + (kind * H + h) * F + tid];
    __syncthreads();
    float x[3];
    float mx = -1e30f;
    #pragma unroll
    for (int j = 0; j < 3; ++j) {
        const int m = tid * 3 + j;
        const float* q = Q + (size_t)m * F;
        float a = 0.f;
        #pragma unroll
        for (int f = 0; f < F; ++f) a += q[f] * s_srk[f];
        x[j] = a * 0.125f;
        mx = fmaxf(mx, x[j]);
    }
    #pragma unroll
    for (int o = 1; o < 64; o <<= 1) mx = fmaxf(mx, __shfl_xor(mx, o));
    const int wid = tid >> 6, lane = tid & 63;
    if (lane == 0) sred[wid] = mx;
    __syncthreads();
    if (tid == 0) { float m2 = sred[0]; for (int i = 1; i < 16; ++i) m2 = fmaxf(m2, sred[i]); sred[0] = m2; }
    __syncthreads();
    mx = sred[0];
    __syncthreads();
    float s = 0.f;
    #pragma unroll
    for (int j = 0; j < 3; ++j) { x[j] = __expf(x[j] - mx); s += x[j]; }
    #pragma unroll
    for (int o = 1; o < 64; o <<= 1) s += __shfl_xor(s, o);
    if (lane == 0) sred[wid] = s;
    __syncthreads();
    if (tid == 0) { float t = 0.f; for (int i = 0; i < 16; ++i) t += sred[i]; sred[0] = t; }
    __syncthreads();
    const float inv = 1.0f / sred[0];
    #pragma unroll
    for (int j = 0; j < 3; ++j) att[tid * 3 + j] = x[j] * inv;
}

// last-writer-wins mask: w[e]=1 iff no e2>e with same (s,d) pair
__global__ __launch_bounds__(256) void winner_kernel(
    const int* __restrict__ s, const int* __restrict__ d,
    int* __restrict__ w, int n)
{
    __shared__ int ss[N_LG], sd[N_LG];
    const int tid = threadIdx.x;
    for (int i = tid; i < n; i += 256) { ss[i] = s[i]; sd[i] = d[i]; }
    __syncthreads();
    const int e = blockIdx.x * 256 + tid;
    if (e >= n) return;
    const int a = ss[e], b = sd[e];
    int win = 1;
    for (int e2 = e + 1; e2 < n; ++e2)
        if (ss[e2] == a && sd[e2] == b) { win = 0; break; }
    w[e] = win;
}

// node_out[src[e],f] += 1/4 * sum_h edge_att[h,e] * Vn[h, dst[e], f]
__global__ __launch_bounds__(64) void scatter_node_kernel(
    const int* __restrict__ src, const int* __restrict__ dst,
    const float* __restrict__ ws, const int* __restrict__ win,
    float* __restrict__ out)
{
    const int e = blockIdx.x;
    if (!win[e]) return;
    const int f = threadIdx.x;
    const int s = src[e], d = dst[e];
    const float* att = ws + OFF_ATT + H * N_NODES;          // edge attention (kind=1)
    const float* V   = ws + OFF_PV;                          // node V (kind=0)
    float acc = 0.f;
    #pragma unroll
    for (int h = 0; h < H; ++h)
        acc += att[h * N_EDGES + e] * V[((size_t)h * N_NODES + d) * F + f];
    atomicAdd(&out[s * F + f], 0.25f * acc);
}

// edge_out[lg_src[l],f] += 1/4 * sum_h node_att[h, dst[lg_src[l]]] * Ve[h, lg_dst[l], f]
__global__ __launch_bounds__(64) void scatter_edge_kernel(
    const int* __restrict__ dst, const int* __restrict__ lg_src, const int* __restrict__ lg_dst,
    const float* __restrict__ ws, const int* __restrict__ win,
    float* __restrict__ out)
{
    const int l = blockIdx.x;
    if (!win[l]) return;
    const int f = threadIdx.x;
    const int e1 = lg_src[l], e2 = lg_dst[l];
    const int conn = dst[e1];
    const float* att = ws + OFF_ATT;                          // node attention (kind=0)
    const float* V   = ws + OFF_PV + (size_t)H * N_EDGES * F; // edge V (kind=1)
    float acc = 0.f;
    #pragma unroll
    for (int h = 0; h < H; ++h)
        acc += att[h * N_NODES + conn] * V[((size_t)h * N_EDGES + e2) * F + f];
    atomicAdd(&out[N_NODES * F + e1 * F + f], 0.25f * acc);
}

extern "C" void kernel_launch(void* const* d_in, const int* in_sizes, int n_in,
                              void* d_out, int out_size, void* d_ws, size_t ws_size,
                              hipStream_t stream)
{
    const float* node_in = (const float*)d_in[0];
    const float* edge_in = (const float*)d_in[1];
    const int* src    = (const int*)d_in[2];
    const int* dst    = (const int*)d_in[3];
    const int* lg_src = (const int*)d_in[4];
    const int* lg_dst = (const int*)d_in[5];
    const float* nqW = (const float*)d_in[6];  const float* nqb = (const float*)d_in[7];
    const float* nkW = (const float*)d_in[8];  const float* nkb = (const float*)d_in[9];
    const float* nvW = (const float*)d_in[10]; const float* nvb = (const float*)d_in[11];
    const float* eqW = (const float*)d_in[12]; const float* eqb = (const float*)d_in[13];
    const float* ekW = (const float*)d_in[14]; const float* ekb = (const float*)d_in[15];
    const float* evW = (const float*)d_in[16]; const float* evb = (const float*)d_in[17];

    float* ws  = (float*)d_ws;
    float* out = (float*)d_out;
    int* win_g  = (int*)(ws + OFF_WING);
    int* win_lg = (int*)(ws + OFF_WINLG);

    hipLaunchKernelGGL(zero_kernel, dim3(393216 / 4 / 256), dim3(256), 0, stream, (float4*)out);
    hipLaunchKernelGGL(proj_kernel, dim3(N_NODES, 2), dim3(576), 0, stream,
                       node_in, edge_in, nqW, nqb, nkW, nkb, nvW, nvb,
                       eqW, eqb, ekW, ekb, evW, evb, ws);
    hipLaunchKernelGGL(srk_kernel, dim3(H, 2), dim3(256), 0, stream, node_in, edge_in, ws);
    hipLaunchKernelGGL(att_kernel, dim3(H, 2), dim3(1024), 0, stream, ws);
    hipLaunchKernelGGL(winner_kernel, dim3((N_EDGES + 255) / 256), dim3(256), 0, stream,
                       src, dst, win_g, N_EDGES);
    hipLaunchKernelGGL(winner_kernel, dim3((N_LG + 255) / 256), dim3(256), 0, stream,
                       lg_src, lg_dst, win_lg, N_LG);
    hipLaunchKernelGGL(scatter_node_kernel, dim3(N_EDGES), dim3(64), 0, stream,
                       src, dst, ws, win_g, out);
    hipLaunchKernelGGL(scatter_edge_kernel, dim3(N_LG), dim3(64), 0, stream,
                       dst, lg_src, lg_dst, ws, win_lg, out);
}

// Round 2
// 235.252 us; speedup vs baseline: 4.3694x; 4.3694x over previous
//
#include <hip/hip_runtime.h>

#define N_NODES 3072
#define N_EDGES 3072
#define N_LG    6144
#define F       64
#define H       4
#define HASH_SZ 16384
#define HASH_MASK (HASH_SZ - 1)

// workspace layout (float offsets)
#define OFF_PQ   0                                  // 2 kinds * H*N*F = 1572864
#define OFF_PV   (OFF_PQ + 2*H*N_NODES*F)           // 1572864
#define OFF_PK   (OFF_PV + 2*H*N_NODES*F)           // 2 kinds * H*N = 24576
#define OFF_SRK  (OFF_PK + 2*H*N_NODES)             // 2*H*F = 512
#define OFF_ATT  (OFF_SRK + 2*H*F)                  // 2 kinds * H*N = 24576
#define OFF_HASH (OFF_ATT + 2*H*N_NODES)            // 4*HASH_SZ ints: keys_g, keys_lg, vals_g, vals_lg

// out zero: 98304 float4 -> 384 blocks. hash: 16384 int4 -> 64 blocks
// (first 32 blocks = keys region -> 0xFFFFFFFF, next 32 = vals region -> 0)
__global__ __launch_bounds__(256) void init_kernel(float4* __restrict__ out, int4* __restrict__ hash) {
    const int b = blockIdx.x, tid = threadIdx.x;
    if (b < 384) {
        out[b * 256 + tid] = make_float4(0.f, 0.f, 0.f, 0.f);
    } else {
        const int idx = (b - 384) * 256 + tid;   // 0..16383 int4
        hash[idx] = (idx < 8192) ? make_int4(-1, -1, -1, -1) : make_int4(0, 0, 0, 0);
    }
}

__device__ __forceinline__ unsigned hash_slot(unsigned key) {
    return (key * 2654435761u >> 16) & HASH_MASK;
}

// last-writer-wins via hash: keys[slot] claimed by CAS, vals[slot] = max edge idx
__global__ __launch_bounds__(256) void hash_insert_kernel(
    const int* __restrict__ s, const int* __restrict__ d,
    unsigned* __restrict__ keys, int* __restrict__ vals, int n)
{
    const int e = blockIdx.x * 256 + threadIdx.x;
    if (e >= n) return;
    const unsigned key = (unsigned)(s[e] * N_NODES + d[e]);
    unsigned idx = hash_slot(key);
    while (true) {
        unsigned prev = atomicCAS(&keys[idx], 0xFFFFFFFFu, key);
        if (prev == 0xFFFFFFFFu || prev == key) { atomicMax(&vals[idx], e); break; }
        idx = (idx + 1) & HASH_MASK;
    }
}

__device__ __forceinline__ int hash_is_winner(
    unsigned key, const unsigned* __restrict__ keys, const int* __restrict__ vals, int e)
{
    unsigned idx = hash_slot(key);
    while (keys[idx] != key) idx = (idx + 1) & HASH_MASK;
    return vals[idx] == e;
}

// grid (3072, 2); block 576. t<256: q col, t<512: v col, t<516: k col.
__global__ __launch_bounds__(576) void proj_kernel(
    const float* __restrict__ node_in, const float* __restrict__ edge_in,
    const float* __restrict__ nqW, const float* __restrict__ nqb,
    const float* __restrict__ nkW, const float* __restrict__ nkb,
    const float* __restrict__ nvW, const float* __restrict__ nvb,
    const float* __restrict__ eqW, const float* __restrict__ eqb,
    const float* __restrict__ ekW, const float* __restrict__ ekb,
    const float* __restrict__ evW, const float* __restrict__ evb,
    float* __restrict__ ws)
{
    const int row = blockIdx.x;
    const int kind = blockIdx.y;
    const int tid = threadIdx.x;
    __shared__ float r[F];
    const float* in = kind ? edge_in : node_in;
    if (tid < F) r[tid] = in[row * F + tid];
    __syncthreads();
    const float* W; const float* b; float* out; int ncols, col;
    if (tid < 256) {
        W = kind ? eqW : nqW; b = kind ? eqb : nqb;
        out = ws + OFF_PQ + (size_t)kind * H * N_NODES * F; ncols = 256; col = tid;
    } else if (tid < 512) {
        W = kind ? evW : nvW; b = kind ? evb : nvb;
        out = ws + OFF_PV + (size_t)kind * H * N_NODES * F; ncols = 256; col = tid - 256;
    } else if (tid < 516) {
        W = kind ? ekW : nkW; b = kind ? ekb : nkb;
        out = ws + OFF_PK + (size_t)kind * H * N_NODES; ncols = 4; col = tid - 512;
    } else return;
    float acc = b[col];
    #pragma unroll
    for (int k = 0; k < F; ++k) acc += r[k] * W[k * ncols + col];
    out[row * ncols + col] = acc;
}

// srk[h,f] = sum_m SR[m,f] * K[h*M+m].  grid (H, 2); block 256 (f = t&63, chunk = t>>6)
__global__ __launch_bounds__(256) void srk_kernel(
    const float* __restrict__ node_in, const float* __restrict__ edge_in,
    float* __restrict__ ws)
{
    const int h = blockIdx.x, kind = blockIdx.y, tid = threadIdx.x;
    const int f = tid & 63, c = tid >> 6;
    const float* SR = kind ? edge_in : node_in;
    const float* K = ws + OFF_PK + kind * H * N_NODES + h * N_NODES;
    float acc = 0.f;
    const int m0 = c * (N_NODES / 4);
    for (int m = m0; m < m0 + N_NODES / 4; ++m)
        acc += SR[m * F + f] * K[m];
    __shared__ float red[256];
    red[tid] = acc;
    __syncthreads();
    if (c == 0)
        ws[OFF_SRK + (kind * H + h) * F + f] = red[f] + red[64 + f] + red[128 + f] + red[192 + f];
}

// x[m] = dot(Q[h,m,:], srk)/8; softmax over m=3072.  grid (H,2); block 1024, 3 m/thread
__global__ __launch_bounds__(1024) void att_kernel(float* __restrict__ ws)
{
    const int h = blockIdx.x, kind = blockIdx.y, tid = threadIdx.x;
    const float* Q = ws + OFF_PQ + (size_t)kind * H * N_NODES * F + (size_t)h * N_NODES * F;
    float* att = ws + OFF_ATT + kind * H * N_NODES + h * N_NODES;
    __shared__ float s_srk[F];
    __shared__ float sred[16];
    if (tid < F) s_srk[tid] = ws[OFF_SRK + (kind * H + h) * F + tid];
    __syncthreads();
    float x[3];
    float mx = -1e30f;
    #pragma unroll
    for (int j = 0; j < 3; ++j) {
        const int m = tid * 3 + j;
        const float* q = Q + (size_t)m * F;
        float a = 0.f;
        #pragma unroll
        for (int f = 0; f < F; ++f) a += q[f] * s_srk[f];
        x[j] = a * 0.125f;
        mx = fmaxf(mx, x[j]);
    }
    #pragma unroll
    for (int o = 1; o < 64; o <<= 1) mx = fmaxf(mx, __shfl_xor(mx, o));
    const int wid = tid >> 6, lane = tid & 63;
    if (lane == 0) sred[wid] = mx;
    __syncthreads();
    if (tid == 0) { float m2 = sred[0]; for (int i = 1; i < 16; ++i) m2 = fmaxf(m2, sred[i]); sred[0] = m2; }
    __syncthreads();
    mx = sred[0];
    __syncthreads();
    float s = 0.f;
    #pragma unroll
    for (int j = 0; j < 3; ++j) { x[j] = __expf(x[j] - mx); s += x[j]; }
    #pragma unroll
    for (int o = 1; o < 64; o <<= 1) s += __shfl_xor(s, o);
    if (lane == 0) sred[wid] = s;
    __syncthreads();
    if (tid == 0) { float t = 0.f; for (int i = 0; i < 16; ++i) t += sred[i]; sred[0] = t; }
    __syncthreads();
    const float inv = 1.0f / sred[0];
    #pragma unroll
    for (int j = 0; j < 3; ++j) att[tid * 3 + j] = x[j] * inv;
}

// node_out[src[e],f] += 1/4 * sum_h edge_att[h,e] * Vn[h, dst[e], f]  (winner edges only)
__global__ __launch_bounds__(64) void scatter_node_kernel(
    const int* __restrict__ src, const int* __restrict__ dst,
    const float* __restrict__ ws,
    const unsigned* __restrict__ keys, const int* __restrict__ vals,
    float* __restrict__ out)
{
    const int e = blockIdx.x;
    const int s = src[e], d = dst[e];
    const unsigned key = (unsigned)(s * N_NODES + d);
    if (!hash_is_winner(key, keys, vals, e)) return;
    const int f = threadIdx.x;
    const float* att = ws + OFF_ATT + H * N_NODES;          // edge attention (kind=1)
    const float* V   = ws + OFF_PV;                          // node V (kind=0)
    float acc = 0.f;
    #pragma unroll
    for (int h = 0; h < H; ++h)
        acc += att[h * N_EDGES + e] * V[((size_t)h * N_NODES + d) * F + f];
    atomicAdd(&out[s * F + f], 0.25f * acc);
}

// edge_out[lg_src[l],f] += 1/4 * sum_h node_att[h, dst[lg_src[l]]] * Ve[h, lg_dst[l], f]
__global__ __launch_bounds__(64) void scatter_edge_kernel(
    const int* __restrict__ dst, const int* __restrict__ lg_src, const int* __restrict__ lg_dst,
    const float* __restrict__ ws,
    const unsigned* __restrict__ keys, const int* __restrict__ vals,
    float* __restrict__ out)
{
    const int l = blockIdx.x;
    const int e1 = lg_src[l], e2 = lg_dst[l];
    const unsigned key = (unsigned)(e1 * N_NODES + e2);
    if (!hash_is_winner(key, keys, vals, l)) return;
    const int f = threadIdx.x;
    const int conn = dst[e1];
    const float* att = ws + OFF_ATT;                          // node attention (kind=0)
    const float* V   = ws + OFF_PV + (size_t)H * N_EDGES * F; // edge V (kind=1)
    float acc = 0.f;
    #pragma unroll
    for (int h = 0; h < H; ++h)
        acc += att[h * N_NODES + conn] * V[((size_t)h * N_EDGES + e2) * F + f];
    atomicAdd(&out[N_NODES * F + e1 * F + f], 0.25f * acc);
}

extern "C" void kernel_launch(void* const* d_in, const int* in_sizes, int n_in,
                              void* d_out, int out_size, void* d_ws, size_t ws_size,
                              hipStream_t stream)
{
    const float* node_in = (const float*)d_in[0];
    const float* edge_in = (const float*)d_in[1];
    const int* src    = (const int*)d_in[2];
    const int* dst    = (const int*)d_in[3];
    const int* lg_src = (const int*)d_in[4];
    const int* lg_dst = (const int*)d_in[5];
    const float* nqW = (const float*)d_in[6];  const float* nqb = (const float*)d_in[7];
    const float* nkW = (const float*)d_in[8];  const float* nkb = (const float*)d_in[9];
    const float* nvW = (const float*)d_in[10]; const float* nvb = (const float*)d_in[11];
    const float* eqW = (const float*)d_in[12]; const float* eqb = (const float*)d_in[13];
    const float* ekW = (const float*)d_in[14]; const float* ekb = (const float*)d_in[15];
    const float* evW = (const float*)d_in[16]; const float* evb = (const float*)d_in[17];

    float* ws  = (float*)d_ws;
    float* out = (float*)d_out;
    unsigned* keys_g  = (unsigned*)(ws + OFF_HASH);
    unsigned* keys_lg = keys_g + HASH_SZ;
    int* vals_g  = (int*)(keys_g + 2 * HASH_SZ);
    int* vals_lg = vals_g + HASH_SZ;

    hipLaunchKernelGGL(init_kernel, dim3(384 + 64), dim3(256), 0, stream,
                       (float4*)out, (int4*)(ws + OFF_HASH));
    hipLaunchKernelGGL(proj_kernel, dim3(N_NODES, 2), dim3(576), 0, stream,
                       node_in, edge_in, nqW, nqb, nkW, nkb, nvW, nvb,
                       eqW, eqb, ekW, ekb, evW, evb, ws);
    hipLaunchKernelGGL(srk_kernel, dim3(H, 2), dim3(256), 0, stream, node_in, edge_in, ws);
    hipLaunchKernelGGL(att_kernel, dim3(H, 2), dim3(1024), 0, stream, ws);
    hipLaunchKernelGGL(hash_insert_kernel, dim3((N_EDGES + 255) / 256), dim3(256), 0, stream,
                       src, dst, keys_g, vals_g, N_EDGES);
    hipLaunchKernelGGL(hash_insert_kernel, dim3((N_LG + 255) / 256), dim3(256), 0, stream,
                       lg_src, lg_dst, keys_lg, vals_lg, N_LG);
    hipLaunchKernelGGL(scatter_node_kernel, dim3(N_EDGES), dim3(64), 0, stream,
                       src, dst, ws, keys_g, vals_g, out);
    hipLaunchKernelGGL(scatter_edge_kernel, dim3(N_LG), dim3(64), 0, stream,
                       dst, lg_src, lg_dst, ws, keys_lg, vals_lg, out);
}

// Round 5
// 150.763 us; speedup vs baseline: 6.8180x; 1.5604x over previous
//
#include <hip/hip_runtime.h>

#define N_NODES 3072
#define N_EDGES 3072
#define N_LG    6144
#define F       64
#define H       4
#define HASH_SZ 16384
#define HASH_MASK (HASH_SZ - 1)

// workspace layout (float offsets)
#define OFF_PV   0                                  // 2 kinds * N*256 = 1572864 (flat [M,256] per kind)
#define OFF_SRK  (OFF_PV + 2*H*N_NODES*F)           // 2*H*F = 512
#define OFF_ATT  (OFF_SRK + 2*H*F)                  // 2 kinds * H*N = 24576
#define OFF_HASH (OFF_ATT + 2*H*N_NODES)            // 4*HASH_SZ ints: keys_g, keys_lg, vals_g, vals_lg

// grid 449 blocks: 384 zero out (98304 float4), 64 hash init (16384 int4), 1 srk zero
__global__ __launch_bounds__(256) void init_kernel(
    float4* __restrict__ out, int4* __restrict__ hash, float* __restrict__ srk)
{
    const int b = blockIdx.x, t = threadIdx.x;
    if (b < 384) {
        out[b * 256 + t] = make_float4(0.f, 0.f, 0.f, 0.f);
    } else if (b < 448) {
        const int idx = (b - 384) * 256 + t;   // 0..16383 int4; first 8192 = keys -> -1, rest vals -> 0
        hash[idx] = (idx < 8192) ? make_int4(-1, -1, -1, -1) : make_int4(0, 0, 0, 0);
    } else {
        srk[t] = 0.f;
        srk[t + 256] = 0.f;
    }
}

__device__ __forceinline__ unsigned hash_slot(unsigned key) {
    return (key * 2654435761u >> 16) & HASH_MASK;
}

// grid 36: b<12 -> g edges (n=3072), else lg (n=6144). last-writer-wins = max edge idx per key.
__global__ __launch_bounds__(256) void hash_insert_kernel(
    const int* __restrict__ src, const int* __restrict__ dst,
    const int* __restrict__ lg_src, const int* __restrict__ lg_dst,
    unsigned* __restrict__ keys_g, int* __restrict__ vals_g,
    unsigned* __restrict__ keys_lg, int* __restrict__ vals_lg)
{
    int b = blockIdx.x;
    const int* s; const int* d; unsigned* keys; int* vals; int n;
    if (b < 12) { s = src;    d = dst;    keys = keys_g;  vals = vals_g;  n = N_EDGES; }
    else { b -= 12; s = lg_src; d = lg_dst; keys = keys_lg; vals = vals_lg; n = N_LG; }
    const int e = b * 256 + threadIdx.x;
    if (e >= n) return;
    const unsigned key = (unsigned)(s[e] * N_NODES + d[e]);
    unsigned idx = hash_slot(key);
    while (true) {
        unsigned prev = atomicCAS(&keys[idx], 0xFFFFFFFFu, key);
        if (prev == 0xFFFFFFFFu || prev == key) { atomicMax(&vals[idx], e); break; }
        idx = (idx + 1) & HASH_MASK;
    }
}

__device__ __forceinline__ int hash_is_winner(
    unsigned key, const unsigned* __restrict__ keys, const int* __restrict__ vals, int e)
{
    unsigned idx = hash_slot(key);
    while (keys[idx] != key) idx = (idx + 1) & HASH_MASK;
    return vals[idx] == e;
}

// fused K-projection + srk partial reduction with CORRECT reshape semantics:
//   k[h,m] = Pk_flat[h*3072+m] = in[(h*3072+m)>>2, :]·Wk[:, (h*3072+m)&3] + bk[(h*3072+m)&3]
// grid (48, 2); block 256.  Block b: h=b/12, g-range [256b, 256b+256), rows r0=64b..+64,
// m-range m0=(b%12)*256..+256.  srk[h,f] += sum_{m in range} in[m,f]*k[h,m]  (atomicAdd)
__global__ __launch_bounds__(256) void srk_kernel(
    const float* __restrict__ node_in, const float* __restrict__ edge_in,
    const float* __restrict__ nkW, const float* __restrict__ nkb,
    const float* __restrict__ ekW, const float* __restrict__ ekb,
    float* __restrict__ srk)
{
    const int kind = blockIdx.y, b = blockIdx.x, t = threadIdx.x;
    const int h = b / 12, m0 = (b % 12) * 256, r0 = b * 64;
    const float* in = kind ? edge_in : node_in;
    const float* Wk = kind ? ekW : nkW;
    const float* bk = kind ? ekb : nkb;
    __shared__ float sin_[64 * 68];      // rows r0..r0+63, padded stride 68
    __shared__ float k_lds[256];         // k[h, m0 + t]
    __shared__ float wk_s[256];          // Wk[j*4+c]
    __shared__ float bk_s[4];
    #pragma unroll
    for (int i = 0; i < 4; ++i) {        // stage 64 rows x 16 float4
        const int idx = t + i * 256;
        const int m = idx >> 4, q = idx & 15;
        float4 v = ((const float4*)(in + (size_t)(r0 + m) * F))[q];
        *(float4*)&sin_[m * 68 + q * 4] = v;
    }
    wk_s[t] = Wk[t];
    if (t < 4) bk_s[t] = bk[t];
    __syncthreads();
    {   // phase 1: k value for local g = t -> row rl = t>>2, col c = t&3
        const int rl = t >> 2, c = t & 3;
        float acc = bk_s[c];
        #pragma unroll
        for (int j = 0; j < F; ++j) acc += sin_[rl * 68 + j] * wk_s[j * 4 + c];
        k_lds[t] = acc;
    }
    __syncthreads();
    {   // phase 2: partial srk over this block's m-range (coalesced global reads of in)
        const int c = t >> 6, f = t & 63;
        float acc = 0.f;
        const float* base = in + (size_t)(m0 + c * 64) * F + f;
        #pragma unroll
        for (int mp = 0; mp < 64; ++mp) acc += base[(size_t)mp * F] * k_lds[c * 64 + mp];
        atomicAdd(&srk[(kind * H + h) * F + f], acc);
    }
}

// fused wq_eff + x + softmax with CORRECT reshape semantics:
//   x[h,m] = ( in[h*768+(m>>2), :]·wq_eff[h, m&3, :] + beff[h, m&3] ) / 8
//   wq_eff[h,c4,j] = sum_f Wq[j*256 + c4*64 + f] * srk[h,f]
// grid (H, 2); block 1024, 3 m/thread.
__global__ __launch_bounds__(1024) void att_kernel(
    const float* __restrict__ node_in, const float* __restrict__ edge_in,
    const float* __restrict__ nqW, const float* __restrict__ nqb,
    const float* __restrict__ eqW, const float* __restrict__ eqb,
    float* __restrict__ ws)
{
    const int h = blockIdx.x, kind = blockIdx.y, tid = threadIdx.x;
    const float* in = kind ? edge_in : node_in;
    const float* Wq = kind ? eqW : nqW;
    const float* bq = kind ? eqb : nqb;
    float* att = ws + OFF_ATT + (kind * H + h) * N_NODES;
    __shared__ float s_srk[F];
    __shared__ float s_w[256];     // [c4][j]
    __shared__ float s_beff[4];
    __shared__ float sred[16];
    if (tid < F) s_srk[tid] = ws[OFF_SRK + (kind * H + h) * F + tid];
    __syncthreads();
    if (tid < 256) {
        const int c4 = tid >> 6, j = tid & 63;
        float we = 0.f;
        #pragma unroll
        for (int f = 0; f < F; ++f) we += Wq[j * 256 + c4 * 64 + f] * s_srk[f];
        s_w[c4 * 64 + j] = we;
    } else if (tid < 260) {
        const int c4 = tid - 256;
        float be = 0.f;
        #pragma unroll
        for (int f = 0; f < F; ++f) be += bq[c4 * 64 + f] * s_srk[f];
        s_beff[c4] = be;
    }
    __syncthreads();
    float x[3];
    float mx = -1e30f;
    #pragma unroll
    for (int j = 0; j < 3; ++j) {
        const int m = tid * 3 + j;
        const int row = h * 768 + (m >> 2);
        const int c4 = m & 3;
        const float4* q4 = (const float4*)(in + (size_t)row * F);
        const float* w = s_w + c4 * 64;
        float a = 0.f;
        #pragma unroll
        for (int i = 0; i < 16; ++i) {
            float4 v = q4[i];
            a += v.x * w[i * 4] + v.y * w[i * 4 + 1] + v.z * w[i * 4 + 2] + v.w * w[i * 4 + 3];
        }
        x[j] = (a + s_beff[c4]) * 0.125f;
        mx = fmaxf(mx, x[j]);
    }
    #pragma unroll
    for (int o = 1; o < 64; o <<= 1) mx = fmaxf(mx, __shfl_xor(mx, o));
    const int wid = tid >> 6, lane = tid & 63;
    if (lane == 0) sred[wid] = mx;
    __syncthreads();
    if (tid == 0) { float m2 = sred[0]; for (int i = 1; i < 16; ++i) m2 = fmaxf(m2, sred[i]); sred[0] = m2; }
    __syncthreads();
    mx = sred[0];
    __syncthreads();
    float s = 0.f;
    #pragma unroll
    for (int j = 0; j < 3; ++j) { x[j] = __expf(x[j] - mx); s += x[j]; }
    #pragma unroll
    for (int o = 1; o < 64; o <<= 1) s += __shfl_xor(s, o);
    if (lane == 0) sred[wid] = s;
    __syncthreads();
    if (tid == 0) { float t = 0.f; for (int i = 0; i < 16; ++i) t += sred[i]; sred[0] = t; }
    __syncthreads();
    const float inv = 1.0f / sred[0];
    #pragma unroll
    for (int j = 0; j < 3; ++j) att[tid * 3 + j] = x[j] * inv;
}

// V projection, row-tiled, stored FLAT [M,256] (reshape semantics handled at read).
// grid (96, 2); block 256; 32 rows/block, thread = one of 256 cols.
__global__ __launch_bounds__(256) void proj_v_kernel(
    const float* __restrict__ node_in, const float* __restrict__ edge_in,
    const float* __restrict__ nvW, const float* __restrict__ nvb,
    const float* __restrict__ evW, const float* __restrict__ evb,
    float* __restrict__ ws)
{
    const int kind = blockIdx.y, col = threadIdx.x;
    const int m0 = blockIdx.x * 32;
    const float* in = kind ? edge_in : node_in;
    const float* W  = kind ? evW : nvW;
    const float* bv = kind ? evb : nvb;
    __shared__ float sin_[32 * 68];
    #pragma unroll
    for (int i = 0; i < 2; ++i) {        // stage 32 rows x 16 float4
        const int idx = col + i * 256;
        const int m = idx >> 4, q = idx & 15;
        float4 v = ((const float4*)(in + (size_t)(m0 + m) * F))[q];
        *(float4*)&sin_[m * 68 + q * 4] = v;
    }
    __syncthreads();
    float acc[32];
    const float b0 = bv[col];
    #pragma unroll
    for (int r = 0; r < 32; ++r) acc[r] = b0;
    #pragma unroll
    for (int k4 = 0; k4 < 16; ++k4) {
        const float w0 = W[(k4 * 4 + 0) * 256 + col];
        const float w1 = W[(k4 * 4 + 1) * 256 + col];
        const float w2 = W[(k4 * 4 + 2) * 256 + col];
        const float w3 = W[(k4 * 4 + 3) * 256 + col];
        #pragma unroll
        for (int r = 0; r < 32; ++r) {
            float4 v = *(const float4*)&sin_[r * 68 + k4 * 4];
            acc[r] = fmaf(v.x, w0, fmaf(v.y, w1, fmaf(v.z, w2, fmaf(v.w, w3, acc[r]))));
        }
    }
    float* V = ws + OFF_PV + (size_t)kind * H * N_NODES * F;
    #pragma unroll
    for (int r = 0; r < 32; ++r)
        V[(size_t)(m0 + r) * 256 + col] = acc[r];   // FLAT [M,256]
}

// merged scatters.  grid 9216 (3072 node + 6144 edge); block 64.
// V is read via reshape-flat indexing: v[h,m,f] = Vflat[h*196608 + m*64 + f]
__global__ __launch_bounds__(64) void scatter_kernel(
    const int* __restrict__ src, const int* __restrict__ dst,
    const int* __restrict__ lg_src, const int* __restrict__ lg_dst,
    const float* __restrict__ ws,
    const unsigned* __restrict__ keys_g, const int* __restrict__ vals_g,
    const unsigned* __restrict__ keys_lg, const int* __restrict__ vals_lg,
    float* __restrict__ out)
{
    const int b = blockIdx.x;
    const int f = threadIdx.x;
    if (b < N_EDGES) {
        const int e = b;
        const int s = src[e], d = dst[e];
        const unsigned key = (unsigned)(s * N_NODES + d);
        if (!hash_is_winner(key, keys_g, vals_g, e)) return;
        const float* att = ws + OFF_ATT + H * N_NODES;          // edge attention (kind=1)
        const float* V   = ws + OFF_PV;                          // node V (kind=0), flat
        float acc = 0.f;
        #pragma unroll
        for (int h = 0; h < H; ++h)
            acc += att[h * N_EDGES + e] * V[(size_t)h * N_NODES * F + (size_t)d * F + f];
        atomicAdd(&out[s * F + f], 0.25f * acc);
    } else {
        const int l = b - N_EDGES;
        const int e1 = lg_src[l], e2 = lg_dst[l];
        const unsigned key = (unsigned)(e1 * N_NODES + e2);
        if (!hash_is_winner(key, keys_lg, vals_lg, l)) return;
        const int conn = dst[e1];
        const float* att = ws + OFF_ATT;                          // node attention (kind=0)
        const float* V   = ws + OFF_PV + (size_t)H * N_EDGES * F; // edge V (kind=1), flat
        float acc = 0.f;
        #pragma unroll
        for (int h = 0; h < H; ++h)
            acc += att[h * N_NODES + conn] * V[(size_t)h * N_EDGES * F + (size_t)e2 * F + f];
        atomicAdd(&out[N_NODES * F + e1 * F + f], 0.25f * acc);
    }
}

extern "C" void kernel_launch(void* const* d_in, const int* in_sizes, int n_in,
                              void* d_out, int out_size, void* d_ws, size_t ws_size,
                              hipStream_t stream)
{
    const float* node_in = (const float*)d_in[0];
    const float* edge_in = (const float*)d_in[1];
    const int* src    = (const int*)d_in[2];
    const int* dst    = (const int*)d_in[3];
    const int* lg_src = (const int*)d_in[4];
    const int* lg_dst = (const int*)d_in[5];
    const float* nqW = (const float*)d_in[6];  const float* nqb = (const float*)d_in[7];
    const float* nkW = (const float*)d_in[8];  const float* nkb = (const float*)d_in[9];
    const float* nvW = (const float*)d_in[10]; const float* nvb = (const float*)d_in[11];
    const float* eqW = (const float*)d_in[12]; const float* eqb = (const float*)d_in[13];
    const float* ekW = (const float*)d_in[14]; const float* ekb = (const float*)d_in[15];
    const float* evW = (const float*)d_in[16]; const float* evb = (const float*)d_in[17];

    float* ws  = (float*)d_ws;
    float* out = (float*)d_out;
    unsigned* keys_g  = (unsigned*)(ws + OFF_HASH);
    unsigned* keys_lg = keys_g + HASH_SZ;
    int* vals_g  = (int*)(keys_g + 2 * HASH_SZ);
    int* vals_lg = vals_g + HASH_SZ;

    hipLaunchKernelGGL(init_kernel, dim3(449), dim3(256), 0, stream,
                       (float4*)out, (int4*)(ws + OFF_HASH), ws + OFF_SRK);
    hipLaunchKernelGGL(hash_insert_kernel, dim3(36), dim3(256), 0, stream,
                       src, dst, lg_src, lg_dst, keys_g, vals_g, keys_lg, vals_lg);
    hipLaunchKernelGGL(srk_kernel, dim3(48, 2), dim3(256), 0, stream,
                       node_in, edge_in, nkW, nkb, ekW, ekb, ws + OFF_SRK);
    hipLaunchKernelGGL(att_kernel, dim3(H, 2), dim3(1024), 0, stream,
                       node_in, edge_in, nqW, nqb, eqW, eqb, ws);
    hipLaunchKernelGGL(proj_v_kernel, dim3(96, 2), dim3(256), 0, stream,
                       node_in, edge_in, nvW, nvb, evW, evb, ws);
    hipLaunchKernelGGL(scatter_kernel, dim3(N_EDGES + N_LG), dim3(64), 0, stream,
                       src, dst, lg_src, lg_dst, ws, keys_g, vals_g, keys_lg, vals_lg, out);
}